// Round 1
// baseline (442.715 us; speedup 1.0000x reference)
//
#include <hip/hip_runtime.h>

typedef _Float16 h8 __attribute__((ext_vector_type(8)));
typedef _Float16 h4 __attribute__((ext_vector_type(4)));
typedef float f4 __attribute__((ext_vector_type(4)));

#define NB 2
#define NT 2048
#define NC 1024
#define NH 16
#define DKK 64
#define DV 176
#define DVP 256
#define OFF 64
#define KV 2112   // OFF + NT

// ---------------- utility kernels ----------------

__global__ void k_f2h4(const float* __restrict__ in, _Float16* __restrict__ out, int n) {
    int i = (blockIdx.x * 256 + threadIdx.x) * 4;
    if (i < n) {
        float4 v = *(const float4*)(in + i);
        h4 h = {(_Float16)v.x, (_Float16)v.y, (_Float16)v.z, (_Float16)v.w};
        *(h4*)(out + i) = h;
    }
}

__global__ void k_zerof(float* __restrict__ p, int n) {
    int i = blockIdx.x * 256 + threadIdx.x;
    if (i < n) p[i] = 0.f;
}

// cached_k (B,H,64,64) -> out_k rows [0,64) and kh (f16)
__global__ void k_copy_ck(const float* __restrict__ ck, float* __restrict__ out_k,
                          _Float16* __restrict__ kh) {
    int i = blockIdx.x * 256 + threadIdx.x;
    if (i >= NB * NH * OFF * DKK) return;
    int bh = i >> 12, rem = i & 4095;
    int pos = rem >> 6, dk = rem & 63;
    int idx = (bh * KV + pos) * DKK + dk;
    float v = ck[i];
    out_k[idx] = v;
    kh[idx] = (_Float16)v;
}

// cached_v (B,H,64,256) -> out_v rows [0,64) (all 256 cols) and vTh (f16, cols<176, transposed)
__global__ void k_copy_cv(const float* __restrict__ cv, float* __restrict__ out_v,
                          _Float16* __restrict__ vTh) {
    int i = blockIdx.x * 256 + threadIdx.x;
    if (i >= NB * NH * OFF * DVP) return;
    int bh = i >> 14, rem = i & 16383;
    int pos = rem >> 8, c = rem & 255;
    float v = cv[i];
    out_v[(bh * KV + pos) * DVP + c] = v;
    if (c < DV) vTh[((size_t)bh * DV + c) * KV + pos] = (_Float16)v;
}

// zero pad cols [176,256) of out_v for new rows [64,2112)
__global__ void k_zpad_v(float* __restrict__ out_v) {
    const int PW = DVP - DV;             // 80
    int i = blockIdx.x * 256 + threadIdx.x;
    const int n = NB * NH * NT * PW;
    if (i >= n) return;
    int bh = i / (NT * PW);
    int rem = i - bh * (NT * PW);
    int t = rem / PW;
    int c = DV + (rem - t * PW);
    out_v[((size_t)bh * KV + OFF + t) * DVP + c] = 0.f;
}

// ---------------- GEMM: qk = x @ W_QK^T ----------------
// M=4096 (b,t), N=2048 (q|k per head), K=1024. 128x128 tile, BK=32, 4 waves 2x2.
__global__ __launch_bounds__(256)
void k_gemm_qk(const _Float16* __restrict__ xh, const _Float16* __restrict__ wh,
               _Float16* __restrict__ qh, _Float16* __restrict__ kh,
               float* __restrict__ out_k) {
    __shared__ _Float16 As[128][40];
    __shared__ _Float16 Bs[128][40];
    const int tid = threadIdx.x;
    const int lane = tid & 63, w = tid >> 6;
    const int lr = lane & 15, lg = lane >> 4;
    const int wm = w >> 1, wn = w & 1;
    const int m0 = blockIdx.y * 128, n0 = blockIdx.x * 128;
    const int ar = tid >> 1, ac = (tid & 1) * 16;  // row, col-offset (halves)

    f4 acc[4][4];
#pragma unroll
    for (int i = 0; i < 4; i++)
#pragma unroll
        for (int j = 0; j < 4; j++) acc[i][j] = (f4){0.f, 0.f, 0.f, 0.f};

    for (int k0 = 0; k0 < NC; k0 += 32) {
        __syncthreads();
        {
            const _Float16* sa = xh + (size_t)(m0 + ar) * NC + k0 + ac;
            *(h8*)&As[ar][ac]     = *(const h8*)sa;
            *(h8*)&As[ar][ac + 8] = *(const h8*)(sa + 8);
            const _Float16* sb = wh + (size_t)(n0 + ar) * NC + k0 + ac;
            *(h8*)&Bs[ar][ac]     = *(const h8*)sb;
            *(h8*)&Bs[ar][ac + 8] = *(const h8*)(sb + 8);
        }
        __syncthreads();
        h8 a[4], b[4];
#pragma unroll
        for (int mt = 0; mt < 4; mt++) a[mt] = *(const h8*)&As[wm * 64 + mt * 16 + lr][lg * 8];
#pragma unroll
        for (int nt = 0; nt < 4; nt++) b[nt] = *(const h8*)&Bs[wn * 64 + nt * 16 + lr][lg * 8];
#pragma unroll
        for (int mt = 0; mt < 4; mt++)
#pragma unroll
            for (int nt = 0; nt < 4; nt++)
                acc[mt][nt] = __builtin_amdgcn_mfma_f32_16x16x32_f16(a[mt], b[nt], acc[mt][nt], 0, 0, 0);
    }

#pragma unroll
    for (int mt = 0; mt < 4; mt++)
#pragma unroll
        for (int nt = 0; nt < 4; nt++)
#pragma unroll
            for (int r = 0; r < 4; r++) {
                int grow = m0 + wm * 64 + mt * 16 + lg * 4 + r;
                int gcol = n0 + wn * 64 + nt * 16 + lr;
                float v = acc[mt][nt][r];
                int b_ = grow >> 11, t = grow & (NT - 1);
                if (gcol < NH * DKK) {
                    int h = gcol >> 6, dk = gcol & 63;
                    qh[((size_t)(b_ * NH + h) * NT + t) * DKK + dk] = (_Float16)v;
                } else {
                    int g2 = gcol - NH * DKK;
                    int h = g2 >> 6, dk = g2 & 63;
                    size_t idx = ((size_t)(b_ * NH + h) * KV + OFF + t) * DKK + dk;
                    out_k[idx] = v;
                    kh[idx] = (_Float16)v;
                }
            }
}

// ---------------- GEMM: v = x @ W_V^T ----------------
// N=2816 (h*176+c). Writes out_v (f32, padded layout) and vT (f16 transposed).
__global__ __launch_bounds__(256)
void k_gemm_v(const _Float16* __restrict__ xh, const _Float16* __restrict__ wh,
              _Float16* __restrict__ vTh, float* __restrict__ out_v) {
    __shared__ _Float16 As[128][40];
    __shared__ _Float16 Bs[128][40];
    const int tid = threadIdx.x;
    const int lane = tid & 63, w = tid >> 6;
    const int lr = lane & 15, lg = lane >> 4;
    const int wm = w >> 1, wn = w & 1;
    const int m0 = blockIdx.y * 128, n0 = blockIdx.x * 128;
    const int ar = tid >> 1, ac = (tid & 1) * 16;

    f4 acc[4][4];
#pragma unroll
    for (int i = 0; i < 4; i++)
#pragma unroll
        for (int j = 0; j < 4; j++) acc[i][j] = (f4){0.f, 0.f, 0.f, 0.f};

    for (int k0 = 0; k0 < NC; k0 += 32) {
        __syncthreads();
        {
            const _Float16* sa = xh + (size_t)(m0 + ar) * NC + k0 + ac;
            *(h8*)&As[ar][ac]     = *(const h8*)sa;
            *(h8*)&As[ar][ac + 8] = *(const h8*)(sa + 8);
            const _Float16* sb = wh + (size_t)(n0 + ar) * NC + k0 + ac;
            *(h8*)&Bs[ar][ac]     = *(const h8*)sb;
            *(h8*)&Bs[ar][ac + 8] = *(const h8*)(sb + 8);
        }
        __syncthreads();
        h8 a[4], b[4];
#pragma unroll
        for (int mt = 0; mt < 4; mt++) a[mt] = *(const h8*)&As[wm * 64 + mt * 16 + lr][lg * 8];
#pragma unroll
        for (int nt = 0; nt < 4; nt++) b[nt] = *(const h8*)&Bs[wn * 64 + nt * 16 + lr][lg * 8];
#pragma unroll
        for (int mt = 0; mt < 4; mt++)
#pragma unroll
            for (int nt = 0; nt < 4; nt++)
                acc[mt][nt] = __builtin_amdgcn_mfma_f32_16x16x32_f16(a[mt], b[nt], acc[mt][nt], 0, 0, 0);
    }

#pragma unroll
    for (int mt = 0; mt < 4; mt++)
#pragma unroll
        for (int nt = 0; nt < 4; nt++)
#pragma unroll
            for (int r = 0; r < 4; r++) {
                int grow = m0 + wm * 64 + mt * 16 + lg * 4 + r;
                int gcol = n0 + wn * 64 + nt * 16 + lr;
                float v = acc[mt][nt][r];
                int b_ = grow >> 11, t = grow & (NT - 1);
                int h = gcol / DV;
                int c = gcol - h * DV;
                out_v[((size_t)(b_ * NH + h) * KV + OFF + t) * DVP + c] = v;
                vTh[((size_t)(b_ * NH + h) * DV + c) * KV + OFF + t] = (_Float16)v;
            }
}

// ---------------- flash attention + head-sum ----------------
// grid: (32 qtiles, 32 bh). block 256 = 4 waves x 16 q-rows. KT=64 keys/tile.
__global__ __launch_bounds__(256)
void k_attn(const _Float16* __restrict__ qh, const _Float16* __restrict__ kh,
            const _Float16* __restrict__ vTh, float* __restrict__ rot) {
    __shared__ _Float16 Ks[64][72];
    __shared__ _Float16 Vs[176][72];
    __shared__ _Float16 Ps[4][16][72];
    const int tid = threadIdx.x, lane = tid & 63, w = tid >> 6;
    const int lr = lane & 15, lg = lane >> 4;
    const int qt = blockIdx.x, bh = blockIdx.y;
    const int b_ = bh >> 4;

    const int qrow = qt * 64 + w * 16 + lr;             // A-frag q-row
    const _Float16* qp = qh + ((size_t)bh * NT + qrow) * DKK;
    h8 aq0 = *(const h8*)(qp + lg * 8);
    h8 aq1 = *(const h8*)(qp + 32 + lg * 8);

    f4 o[11];
#pragma unroll
    for (int i = 0; i < 11; i++) o[i] = (f4){0.f, 0.f, 0.f, 0.f};
    float m_r[4] = {-1e30f, -1e30f, -1e30f, -1e30f};
    float l_r[4] = {0.f, 0.f, 0.f, 0.f};

    const int qbase = qt * 64 + w * 16 + lg * 4;        // D-layout q-row base
    const int nkt = qt + 2;

    for (int kt = 0; kt < nkt; kt++) {
        __syncthreads();
        for (int i = tid; i < 512; i += 256) {          // K tile 64x64
            int r = i >> 3, c = i & 7;
            *(h8*)&Ks[r][c * 8] = *(const h8*)&kh[((size_t)bh * KV + kt * 64 + r) * DKK + c * 8];
        }
        for (int i = tid; i < 1408; i += 256) {         // V tile (transposed) 176x64
            int r = i >> 3, c = i & 7;
            *(h8*)&Vs[r][c * 8] = *(const h8*)&vTh[((size_t)bh * DV + r) * KV + kt * 64 + c * 8];
        }
        __syncthreads();

        f4 s[4];
#pragma unroll
        for (int nt = 0; nt < 4; nt++) {
            h8 bk0 = *(const h8*)&Ks[nt * 16 + lr][lg * 8];
            h8 bk1 = *(const h8*)&Ks[nt * 16 + lr][32 + lg * 8];
            f4 st = (f4){0.f, 0.f, 0.f, 0.f};
            st = __builtin_amdgcn_mfma_f32_16x16x32_f16(aq0, bk0, st, 0, 0, 0);
            st = __builtin_amdgcn_mfma_f32_16x16x32_f16(aq1, bk1, st, 0, 0, 0);
            s[nt] = st;
        }

        // online softmax, rows = qbase + r, cols = kt*64 + nt*16 + lr
#pragma unroll
        for (int r = 0; r < 4; r++) {
            int qp_ = qbase + r;
            float sv[4];
            float rowmax = -1e30f;
#pragma unroll
            for (int nt = 0; nt < 4; nt++) {
                int key = kt * 64 + nt * 16 + lr;
                float v = s[nt][r] * 0.125f;
                if (key > qp_ + 64) v = -1e30f;         // causal (+OFFSET shift)
                sv[nt] = v;
                rowmax = fmaxf(rowmax, v);
            }
#pragma unroll
            for (int mm = 1; mm < 16; mm <<= 1) rowmax = fmaxf(rowmax, __shfl_xor(rowmax, mm));
            float mnew = fmaxf(m_r[r], rowmax);
            float corr = __expf(m_r[r] - mnew);
            float rowsum = 0.f;
#pragma unroll
            for (int nt = 0; nt < 4; nt++) {
                float p = __expf(sv[nt] - mnew);
                rowsum += p;
                Ps[w][lg * 4 + r][nt * 16 + lr] = (_Float16)p;
            }
#pragma unroll
            for (int mm = 1; mm < 16; mm <<= 1) rowsum += __shfl_xor(rowsum, mm);
            l_r[r] = l_r[r] * corr + rowsum;
            m_r[r] = mnew;
#pragma unroll
            for (int nt = 0; nt < 11; nt++) o[nt][r] *= corr;
        }
        __syncthreads();   // Ps D->A relayout visible (also keeps waves in step)

        // PV: o += P @ V
#pragma unroll
        for (int ks = 0; ks < 2; ks++) {
            h8 ap = *(const h8*)&Ps[w][lr][ks * 32 + lg * 8];
#pragma unroll
            for (int nt = 0; nt < 11; nt++) {
                h8 bv = *(const h8*)&Vs[nt * 16 + lr][ks * 32 + lg * 8];
                o[nt] = __builtin_amdgcn_mfma_f32_16x16x32_f16(ap, bv, o[nt], 0, 0, 0);
            }
        }
    }

#pragma unroll
    for (int r = 0; r < 4; r++) {
        float inv = 1.f / l_r[r];
        int t = qbase + r;
#pragma unroll
        for (int nt = 0; nt < 11; nt++) {
            float val = o[nt][r] * inv;
            atomicAdd(&rot[((size_t)b_ * NT + t) * DV + nt * 16 + lr], val);
        }
    }
}

// ---------------- per-token Kronecker rotation via expm ----------------
__device__ __forceinline__ int triu16(int r, int c) { return r * 15 - (r * (r - 1)) / 2 + (c - r - 1); }
__device__ __forceinline__ int triu8(int r, int c)  { return r * 7  - (r * (r - 1)) / 2 + (c - r - 1); }

__global__ __launch_bounds__(64)
void k_rotate(const float* __restrict__ x, const float* __restrict__ rot,
              float* __restrict__ y) {
    __shared__ float A16[16][16], Ta[16][16], Tb[16][16];
    __shared__ float A8[2][8][8], T8a[2][8][8], T8b[2][8][8];
    __shared__ float pbuf[176];
    __shared__ float xt[1024], t1[1024], t2[1024];
    const int tok = blockIdx.x;
    const int lane = threadIdx.x;

    for (int i = lane; i < 176; i += 64) pbuf[i] = rot[(size_t)tok * DV + i];
    for (int i = lane; i < 1024; i += 64) xt[i] = x[(size_t)tok * NC + i];
    __syncthreads();

    // build skew-symmetric matrices
#pragma unroll
    for (int j = 0; j < 4; j++) {
        int e = lane * 4 + j, r = e >> 4, c = e & 15;
        float v = 0.f;
        if (r < c) v = pbuf[triu16(r, c)];
        else if (r > c) v = -pbuf[triu16(c, r)];
        A16[r][c] = v;
    }
    {
        int r = lane >> 3, c = lane & 7;
#pragma unroll
        for (int m = 0; m < 2; m++) {
            float v = 0.f;
            if (r < c) v = pbuf[120 + m * 28 + triu8(r, c)];
            else if (r > c) v = -pbuf[120 + m * 28 + triu8(c, r)];
            A8[m][r][c] = v;
        }
    }
    __syncthreads();

    // ---- expm(A16): scale, 12-term Taylor (Horner), square ----
    float rn = 0.f;
    if (lane < 16) {
#pragma unroll
        for (int c = 0; c < 16; c++) rn += fabsf(A16[lane][c]);
    }
#pragma unroll
    for (int mm = 1; mm < 16; mm <<= 1) rn = fmaxf(rn, __shfl_xor(rn, mm));
    rn = __shfl(rn, 0);
    int s = 0;
    while (rn > 0.5f && s < 60) { rn *= 0.5f; s++; }
    const float sc16 = exp2f((float)(-s));
    __syncthreads();
#pragma unroll
    for (int j = 0; j < 4; j++) { int e = lane * 4 + j; A16[e >> 4][e & 15] *= sc16; }
    __syncthreads();
#pragma unroll
    for (int j = 0; j < 4; j++) {
        int e = lane * 4 + j, r = e >> 4, c = e & 15;
        Ta[r][c] = (r == c ? 1.f : 0.f) + A16[r][c] * (1.f / 12.f);
    }
    __syncthreads();
    float (*Tc)[16] = Ta, (*Tn)[16] = Tb;
    for (int k = 11; k >= 1; k--) {
#pragma unroll
        for (int j = 0; j < 4; j++) {
            int e = lane * 4 + j, r = e >> 4, c = e & 15;
            float acc = 0.f;
#pragma unroll
            for (int q = 0; q < 16; q++) acc += A16[r][q] * Tc[q][c];
            Tn[r][c] = acc * (1.f / (float)k) + (r == c ? 1.f : 0.f);
        }
        __syncthreads();
        float (*tmp)[16] = Tc; Tc = Tn; Tn = tmp;
    }
    for (int it = 0; it < s; it++) {
#pragma unroll
        for (int j = 0; j < 4; j++) {
            int e = lane * 4 + j, r = e >> 4, c = e & 15;
            float acc = 0.f;
#pragma unroll
            for (int q = 0; q < 16; q++) acc += Tc[r][q] * Tc[q][c];
            Tn[r][c] = acc;
        }
        __syncthreads();
        float (*tmp)[16] = Tc; Tc = Tn; Tn = tmp;
    }
    // Tc now holds R1 (16x16)

    // ---- expm for the two 8x8s ----
    float (*R2p)[8] = T8a[0];
    float (*R3p)[8] = T8a[1];
    {
        int r = lane >> 3, c = lane & 7;
        for (int m = 0; m < 2; m++) {
            float rn8 = 0.f;
            if (lane < 8) {
#pragma unroll
                for (int cc = 0; cc < 8; cc++) rn8 += fabsf(A8[m][lane][cc]);
            }
#pragma unroll
            for (int mm = 1; mm < 8; mm <<= 1) rn8 = fmaxf(rn8, __shfl_xor(rn8, mm));
            rn8 = __shfl(rn8, 0);
            int s8 = 0;
            while (rn8 > 0.5f && s8 < 60) { rn8 *= 0.5f; s8++; }
            float sc8 = exp2f((float)(-s8));
            __syncthreads();
            A8[m][r][c] *= sc8;
            __syncthreads();
            T8a[m][r][c] = (r == c ? 1.f : 0.f) + A8[m][r][c] * (1.f / 12.f);
            __syncthreads();
            float (*tc)[8] = T8a[m], (*tn)[8] = T8b[m];
            for (int k = 11; k >= 1; k--) {
                float acc = 0.f;
#pragma unroll
                for (int q = 0; q < 8; q++) acc += A8[m][r][q] * tc[q][c];
                tn[r][c] = acc * (1.f / (float)k) + (r == c ? 1.f : 0.f);
                __syncthreads();
                float (*tmp)[8] = tc; tc = tn; tn = tmp;
            }
            for (int it = 0; it < s8; it++) {
                float acc = 0.f;
#pragma unroll
                for (int q = 0; q < 8; q++) acc += tc[r][q] * tc[q][c];
                tn[r][c] = acc;
                __syncthreads();
                float (*tmp)[8] = tc; tc = tn; tn = tmp;
            }
            if (m == 0) R2p = tc; else R3p = tc;
        }
    }
    __syncthreads();

    // ---- apply y = (R1 (x) R2 (x) R3) x ----
    for (int o = lane; o < 1024; o += 64) {           // axis cc with R3
        int c = o & 7, base = o & ~7;
        float acc = 0.f;
#pragma unroll
        for (int j = 0; j < 8; j++) acc += R3p[c][j] * xt[base + j];
        t1[o] = acc;
    }
    __syncthreads();
    for (int o = lane; o < 1024; o += 64) {           // axis bb with R2
        int c = o & 7, bb = (o >> 3) & 7, a = o >> 6;
        float acc = 0.f;
#pragma unroll
        for (int j = 0; j < 8; j++) acc += R2p[bb][j] * t1[a * 64 + j * 8 + c];
        t2[o] = acc;
    }
    __syncthreads();
    for (int o = lane; o < 1024; o += 64) {           // axis a with R1
        int rr = o & 63, a = o >> 6;
        float acc = 0.f;
#pragma unroll
        for (int j = 0; j < 16; j++) acc += Tc[a][j] * t2[j * 64 + rr];
        y[(size_t)tok * NC + o] = acc;
    }
}

// ---------------- launcher ----------------
extern "C" void kernel_launch(void* const* d_in, const int* in_sizes, int n_in,
                              void* d_out, int out_size, void* d_ws, size_t ws_size,
                              hipStream_t stream) {
    const float* x   = (const float*)d_in[0];
    const float* ck  = (const float*)d_in[1];
    const float* cv  = (const float*)d_in[2];
    const float* wqk = (const float*)d_in[3];
    const float* wv  = (const float*)d_in[4];

    float* out_y = (float*)d_out;
    float* out_k = out_y + (size_t)NB * NT * NC;            // 4,194,304
    float* out_v = out_k + (size_t)NB * NH * KV * DKK;      // +4,325,376

    char* ws = (char*)d_ws;
    _Float16* xh   = (_Float16*)ws;  ws += (size_t)NB * NT * NC * 2;            // 8,388,608
    _Float16* wqkh = (_Float16*)ws;  ws += (size_t)2 * NH * DKK * NC * 2;       // 4,194,304
    _Float16* wvh  = (_Float16*)ws;  ws += (size_t)NH * DV * NC * 2;            // 5,767,168
    _Float16* qh   = (_Float16*)ws;  ws += (size_t)NB * NH * NT * DKK * 2;      // 8,388,608
    _Float16* kh   = (_Float16*)ws;  ws += (size_t)NB * NH * KV * DKK * 2;      // 8,650,752
    _Float16* vTh  = (_Float16*)ws;  ws += (size_t)NB * NH * DV * KV * 2;       // 23,789,568
    float*    rotb = (float*)ws;     ws += (size_t)NB * NT * DV * 4;            // 2,883,584

    const int nx  = NB * NT * NC;          // 4,194,304
    const int nqk = 2 * NH * DKK * NC;     // 2,097,152
    const int nwv = NH * DV * NC;          // 2,883,584
    const int nrot = NB * NT * DV;         // 720,896

    k_f2h4<<<dim3((nx / 4 + 255) / 256), dim3(256), 0, stream>>>(x, xh, nx);
    k_f2h4<<<dim3((nqk / 4 + 255) / 256), dim3(256), 0, stream>>>(wqk, wqkh, nqk);
    k_f2h4<<<dim3((nwv / 4 + 255) / 256), dim3(256), 0, stream>>>(wv, wvh, nwv);
    k_zerof<<<dim3((nrot + 255) / 256), dim3(256), 0, stream>>>(rotb, nrot);

    k_copy_ck<<<dim3((NB * NH * OFF * DKK + 255) / 256), dim3(256), 0, stream>>>(ck, out_k, kh);
    k_copy_cv<<<dim3((NB * NH * OFF * DVP + 255) / 256), dim3(256), 0, stream>>>(cv, out_v, vTh);
    k_zpad_v<<<dim3((NB * NH * NT * (DVP - DV) + 255) / 256), dim3(256), 0, stream>>>(out_v);

    k_gemm_qk<<<dim3(16, 32), dim3(256), 0, stream>>>(xh, wqkh, qh, kh, out_k);
    k_gemm_v<<<dim3(22, 32), dim3(256), 0, stream>>>(xh, wvh, vTh, out_v);

    k_attn<<<dim3(32, 32), dim3(256), 0, stream>>>(qh, kh, vTh, rotb);

    k_rotate<<<dim3(NB * NT), dim3(64), 0, stream>>>(x, rotb, out_y);
}

// Round 2
// 409.512 us; speedup vs baseline: 1.0811x; 1.0811x over previous
//
#include <hip/hip_runtime.h>

typedef _Float16 h8 __attribute__((ext_vector_type(8)));
typedef _Float16 h4 __attribute__((ext_vector_type(4)));
typedef float f4 __attribute__((ext_vector_type(4)));

#define NB 2
#define NT 2048
#define NC 1024
#define NH 16
#define DKK 64
#define DV 176
#define DVP 256
#define OFF 64
#define KV 2112   // OFF + NT

__device__ __forceinline__ void load_lds16(const _Float16* g, _Float16* l) {
    __builtin_amdgcn_global_load_lds(
        (const __attribute__((address_space(1))) void*)g,
        (__attribute__((address_space(3))) void*)l, 16, 0, 0);
}

// ---------------- utility kernels ----------------

__global__ void k_f2h4(const float* __restrict__ in, _Float16* __restrict__ out, int n) {
    int i = (blockIdx.x * 256 + threadIdx.x) * 4;
    if (i < n) {
        float4 v = *(const float4*)(in + i);
        h4 h = {(_Float16)v.x, (_Float16)v.y, (_Float16)v.z, (_Float16)v.w};
        *(h4*)(out + i) = h;
    }
}

__global__ void k_zerof(float* __restrict__ p, int n) {
    int i = blockIdx.x * 256 + threadIdx.x;
    if (i < n) p[i] = 0.f;
}

__global__ void k_copy_ck(const float* __restrict__ ck, float* __restrict__ out_k,
                          _Float16* __restrict__ kh) {
    int i = blockIdx.x * 256 + threadIdx.x;
    if (i >= NB * NH * OFF * DKK) return;
    int bh = i >> 12, rem = i & 4095;
    int pos = rem >> 6, dk = rem & 63;
    int idx = (bh * KV + pos) * DKK + dk;
    float v = ck[i];
    out_k[idx] = v;
    kh[idx] = (_Float16)v;
}

__global__ void k_copy_cv(const float* __restrict__ cv, float* __restrict__ out_v,
                          _Float16* __restrict__ vTh) {
    int i = blockIdx.x * 256 + threadIdx.x;
    if (i >= NB * NH * OFF * DVP) return;
    int bh = i >> 14, rem = i & 16383;
    int pos = rem >> 8, c = rem & 255;
    float v = cv[i];
    out_v[(bh * KV + pos) * DVP + c] = v;
    if (c < DV) vTh[((size_t)bh * DV + c) * KV + pos] = (_Float16)v;
}

__global__ void k_zpad_v(float* __restrict__ out_v) {
    const int PW = DVP - DV;             // 80
    int i = blockIdx.x * 256 + threadIdx.x;
    const int n = NB * NH * NT * PW;
    if (i >= n) return;
    int bh = i / (NT * PW);
    int rem = i - bh * (NT * PW);
    int t = rem / PW;
    int c = DV + (rem - t * PW);
    out_v[((size_t)bh * KV + OFF + t) * DVP + c] = 0.f;
}

// ---------------- GEMM: qk = x @ W_QK^T (m97-style staging) ----------------
__global__ __launch_bounds__(256)
void k_gemm_qk(const _Float16* __restrict__ xh, const _Float16* __restrict__ wh,
               _Float16* __restrict__ qh, _Float16* __restrict__ kh,
               float* __restrict__ out_k) {
    __shared__ _Float16 As[128][32];
    __shared__ _Float16 Bs[128][32];
    const int tid = threadIdx.x;
    const int lane = tid & 63, w = tid >> 6;
    const int lr = lane & 15, lg = lane >> 4;
    const int wm = w >> 1, wn = w & 1;
    const int m0 = blockIdx.y * 128, n0 = blockIdx.x * 128;
    const int srow = lane >> 2, scol = (lane & 3) * 8;

    f4 acc[4][4];
#pragma unroll
    for (int i = 0; i < 4; i++)
#pragma unroll
        for (int j = 0; j < 4; j++) acc[i][j] = (f4){0.f, 0.f, 0.f, 0.f};

    for (int k0 = 0; k0 < NC; k0 += 32) {
        __syncthreads();
#pragma unroll
        for (int j = 0; j < 2; j++) {
            int rb = (w * 2 + j) * 16;
            load_lds16(&xh[(size_t)(m0 + rb + srow) * NC + k0 + scol], &As[rb][0]);
            load_lds16(&wh[(size_t)(n0 + rb + srow) * NC + k0 + scol], &Bs[rb][0]);
        }
        __syncthreads();
        h8 a[4], b[4];
#pragma unroll
        for (int mt = 0; mt < 4; mt++) a[mt] = *(const h8*)&As[wm * 64 + mt * 16 + lr][lg * 8];
#pragma unroll
        for (int nt = 0; nt < 4; nt++) b[nt] = *(const h8*)&Bs[wn * 64 + nt * 16 + lr][lg * 8];
#pragma unroll
        for (int mt = 0; mt < 4; mt++)
#pragma unroll
            for (int nt = 0; nt < 4; nt++)
                acc[mt][nt] = __builtin_amdgcn_mfma_f32_16x16x32_f16(a[mt], b[nt], acc[mt][nt], 0, 0, 0);
    }

#pragma unroll
    for (int mt = 0; mt < 4; mt++)
#pragma unroll
        for (int nt = 0; nt < 4; nt++)
#pragma unroll
            for (int r = 0; r < 4; r++) {
                int grow = m0 + wm * 64 + mt * 16 + lg * 4 + r;
                int gcol = n0 + wn * 64 + nt * 16 + lr;
                float v = acc[mt][nt][r];
                int b_ = grow >> 11, t = grow & (NT - 1);
                if (gcol < NH * DKK) {
                    int h = gcol >> 6, dk = gcol & 63;
                    qh[((size_t)(b_ * NH + h) * NT + t) * DKK + dk] = (_Float16)v;
                } else {
                    int g2 = gcol - NH * DKK;
                    int h = g2 >> 6, dk = g2 & 63;
                    size_t idx = ((size_t)(b_ * NH + h) * KV + OFF + t) * DKK + dk;
                    out_k[idx] = v;
                    kh[idx] = (_Float16)v;
                }
            }
}

// ---------------- GEMM: v = x @ W_V^T ----------------
__global__ __launch_bounds__(256)
void k_gemm_v(const _Float16* __restrict__ xh, const _Float16* __restrict__ wh,
              _Float16* __restrict__ vTh, float* __restrict__ out_v) {
    __shared__ _Float16 As[128][32];
    __shared__ _Float16 Bs[128][32];
    const int tid = threadIdx.x;
    const int lane = tid & 63, w = tid >> 6;
    const int lr = lane & 15, lg = lane >> 4;
    const int wm = w >> 1, wn = w & 1;
    const int m0 = blockIdx.y * 128, n0 = blockIdx.x * 128;
    const int srow = lane >> 2, scol = (lane & 3) * 8;

    f4 acc[4][4];
#pragma unroll
    for (int i = 0; i < 4; i++)
#pragma unroll
        for (int j = 0; j < 4; j++) acc[i][j] = (f4){0.f, 0.f, 0.f, 0.f};

    for (int k0 = 0; k0 < NC; k0 += 32) {
        __syncthreads();
#pragma unroll
        for (int j = 0; j < 2; j++) {
            int rb = (w * 2 + j) * 16;
            load_lds16(&xh[(size_t)(m0 + rb + srow) * NC + k0 + scol], &As[rb][0]);
            load_lds16(&wh[(size_t)(n0 + rb + srow) * NC + k0 + scol], &Bs[rb][0]);
        }
        __syncthreads();
        h8 a[4], b[4];
#pragma unroll
        for (int mt = 0; mt < 4; mt++) a[mt] = *(const h8*)&As[wm * 64 + mt * 16 + lr][lg * 8];
#pragma unroll
        for (int nt = 0; nt < 4; nt++) b[nt] = *(const h8*)&Bs[wn * 64 + nt * 16 + lr][lg * 8];
#pragma unroll
        for (int mt = 0; mt < 4; mt++)
#pragma unroll
            for (int nt = 0; nt < 4; nt++)
                acc[mt][nt] = __builtin_amdgcn_mfma_f32_16x16x32_f16(a[mt], b[nt], acc[mt][nt], 0, 0, 0);
    }

#pragma unroll
    for (int mt = 0; mt < 4; mt++)
#pragma unroll
        for (int nt = 0; nt < 4; nt++)
#pragma unroll
            for (int r = 0; r < 4; r++) {
                int grow = m0 + wm * 64 + mt * 16 + lg * 4 + r;
                int gcol = n0 + wn * 64 + nt * 16 + lr;
                float v = acc[mt][nt][r];
                int b_ = grow >> 11, t = grow & (NT - 1);
                int h = gcol / DV;
                int c = gcol - h * DV;
                out_v[((size_t)(b_ * NH + h) * KV + OFF + t) * DVP + c] = v;
                vTh[((size_t)(b_ * NH + h) * DV + c) * KV + OFF + t] = (_Float16)v;
            }
}

// ---------------- flash attention + head-sum ----------------
// 1024 blocks; in-kernel remap: bh = (n&7) + 8*((n>>3)&3)  (XCD-affine),
// qt = 31 - (n>>5)  (LPT: long blocks first). 4 waves x 16 q-rows.
// K double-buffered in LDS via global_load_lds with XOR swizzle; V read from
// global (vTh transposed, L2-resident); Ps wave-private (no barrier).
__global__ __launch_bounds__(256, 4)
void k_attn(const _Float16* __restrict__ qh, const _Float16* __restrict__ kh,
            const _Float16* __restrict__ vTh, float* __restrict__ rot) {
    __shared__ _Float16 Ks[2][64][64];   // 16 KB, dbuf, swizzled cols
    __shared__ _Float16 Ps[4][16][72];   // 9.2 KB
    const int tid = threadIdx.x, lane = tid & 63, w = tid >> 6;
    const int lr = lane & 15, lg = lane >> 4;
    const int n = blockIdx.x;
    const int m = n >> 3;
    const int bh = (n & 7) + 8 * (m & 3);
    const int qt = 31 - (m >> 2);
    const int b_ = bh >> 4;

    const int qrow = qt * 64 + w * 16 + lr;
    const _Float16* qp = qh + ((size_t)bh * NT + qrow) * DKK;
    h8 aq0 = *(const h8*)(qp + lg * 8);
    h8 aq1 = *(const h8*)(qp + 32 + lg * 8);

    f4 o[11];
#pragma unroll
    for (int i = 0; i < 11; i++) o[i] = (f4){0.f, 0.f, 0.f, 0.f};
    float m_r[4] = {-1e30f, -1e30f, -1e30f, -1e30f};
    float l_r[4] = {0.f, 0.f, 0.f, 0.f};

    const int qbase = qt * 64 + w * 16 + lg * 4;
    const int nkt = qt + 2;

    // stage 64x64-half K tile: 2 wave-calls of 8 rows x 128B each.
    // lane l -> row rb + (l>>3), LDS slot col16 = l&7 holds global col16
    // (l&7)^(l>>3)  => slot c holds global col c ^ (row&7)  (XOR swizzle).
    auto stageK = [&](int buf, int kt) {
#pragma unroll
        for (int j = 0; j < 2; j++) {
            int rb = (w * 2 + j) * 8;
            int row = rb + (lane >> 3);
            int c16 = (lane & 7) ^ (lane >> 3);
            load_lds16(&kh[((size_t)bh * KV + kt * 64 + row) * DKK + c16 * 8],
                       &Ks[buf][rb][0]);
        }
    };

    stageK(0, 0);
    int cur = 0;

    for (int kt = 0; kt < nkt; kt++) {
        __builtin_amdgcn_s_barrier();          // all waves done reading buf cur^1
        if (kt + 1 < nkt) {
            stageK(cur ^ 1, kt + 1);
            asm volatile("s_waitcnt vmcnt(2)" ::: "memory");   // prev stage done
        } else {
            asm volatile("s_waitcnt vmcnt(0)" ::: "memory");
        }
        __builtin_amdgcn_s_barrier();          // buf cur visible to all
        __builtin_amdgcn_sched_barrier(0);

        f4 s[4];
#pragma unroll
        for (int nt = 0; nt < 4; nt++) {
            int krow = nt * 16 + lr;
            h8 bk0 = *(const h8*)&Ks[cur][krow][(lg ^ (lr & 7)) * 8];
            h8 bk1 = *(const h8*)&Ks[cur][krow][((lg + 4) ^ (lr & 7)) * 8];
            f4 st = (f4){0.f, 0.f, 0.f, 0.f};
            st = __builtin_amdgcn_mfma_f32_16x16x32_f16(aq0, bk0, st, 0, 0, 0);
            st = __builtin_amdgcn_mfma_f32_16x16x32_f16(aq1, bk1, st, 0, 0, 0);
            s[nt] = st;
        }

#pragma unroll
        for (int r = 0; r < 4; r++) {
            int qp_ = qbase + r;
            float sv[4];
            float rowmax = -1e30f;
#pragma unroll
            for (int nt = 0; nt < 4; nt++) {
                int key = kt * 64 + nt * 16 + lr;
                float v = s[nt][r] * 0.125f;
                if (key > qp_ + 64) v = -1e30f;
                sv[nt] = v;
                rowmax = fmaxf(rowmax, v);
            }
#pragma unroll
            for (int mm = 1; mm < 16; mm <<= 1) rowmax = fmaxf(rowmax, __shfl_xor(rowmax, mm));
            float mnew = fmaxf(m_r[r], rowmax);
            float corr = __expf(m_r[r] - mnew);
            float rowsum = 0.f;
#pragma unroll
            for (int nt = 0; nt < 4; nt++) {
                float p = __expf(sv[nt] - mnew);
                rowsum += p;
                Ps[w][lg * 4 + r][nt * 16 + lr] = (_Float16)p;
            }
#pragma unroll
            for (int mm = 1; mm < 16; mm <<= 1) rowsum += __shfl_xor(rowsum, mm);
            l_r[r] = l_r[r] * corr + rowsum;
            m_r[r] = mnew;
#pragma unroll
            for (int nt = 0; nt < 11; nt++) o[nt][r] *= corr;
        }
        __builtin_amdgcn_sched_barrier(0);     // Ps writes before Ps reads (same wave)

#pragma unroll
        for (int ks = 0; ks < 2; ks++) {
            h8 ap = *(const h8*)&Ps[w][lr][ks * 32 + lg * 8];
            const _Float16* vb = vTh + (size_t)bh * DV * KV + (size_t)(kt * 64 + ks * 32 + lg * 8);
#pragma unroll
            for (int nt = 0; nt < 11; nt++) {
                h8 bv = *(const h8*)(vb + (size_t)(nt * 16 + lr) * KV);
                o[nt] = __builtin_amdgcn_mfma_f32_16x16x32_f16(ap, bv, o[nt], 0, 0, 0);
            }
        }
        cur ^= 1;
    }

#pragma unroll
    for (int r = 0; r < 4; r++) {
        float inv = 1.f / l_r[r];
        int t = qbase + r;
#pragma unroll
        for (int nt = 0; nt < 11; nt++) {
            float val = o[nt][r] * inv;
            atomicAdd(&rot[((size_t)b_ * NT + t) * DV + nt * 16 + lr], val);
        }
    }
}

// ---------------- per-token Kronecker rotation via expm ----------------
__device__ __forceinline__ int triu16(int r, int c) { return r * 15 - (r * (r - 1)) / 2 + (c - r - 1); }
__device__ __forceinline__ int triu8(int r, int c)  { return r * 7  - (r * (r - 1)) / 2 + (c - r - 1); }

__global__ __launch_bounds__(64)
void k_rotate(const float* __restrict__ x, const float* __restrict__ rot,
              float* __restrict__ y) {
    __shared__ float A16[16][16], Ta[16][16], Tb[16][16];
    __shared__ float A8[2][8][8], T8a[2][8][8], T8b[2][8][8];
    __shared__ float pbuf[176];
    __shared__ float xt[1024], t1[1024], t2[1024];
    const int tok = blockIdx.x;
    const int lane = threadIdx.x;

    for (int i = lane; i < 176; i += 64) pbuf[i] = rot[(size_t)tok * DV + i];
    for (int i = lane; i < 1024; i += 64) xt[i] = x[(size_t)tok * NC + i];
    __syncthreads();

#pragma unroll
    for (int j = 0; j < 4; j++) {
        int e = lane * 4 + j, r = e >> 4, c = e & 15;
        float v = 0.f;
        if (r < c) v = pbuf[triu16(r, c)];
        else if (r > c) v = -pbuf[triu16(c, r)];
        A16[r][c] = v;
    }
    {
        int r = lane >> 3, c = lane & 7;
#pragma unroll
        for (int m = 0; m < 2; m++) {
            float v = 0.f;
            if (r < c) v = pbuf[120 + m * 28 + triu8(r, c)];
            else if (r > c) v = -pbuf[120 + m * 28 + triu8(c, r)];
            A8[m][r][c] = v;
        }
    }
    __syncthreads();

    float rn = 0.f;
    if (lane < 16) {
#pragma unroll
        for (int c = 0; c < 16; c++) rn += fabsf(A16[lane][c]);
    }
#pragma unroll
    for (int mm = 1; mm < 16; mm <<= 1) rn = fmaxf(rn, __shfl_xor(rn, mm));
    rn = __shfl(rn, 0);
    int s = 0;
    while (rn > 0.5f && s < 60) { rn *= 0.5f; s++; }
    const float sc16 = exp2f((float)(-s));
    __syncthreads();
#pragma unroll
    for (int j = 0; j < 4; j++) { int e = lane * 4 + j; A16[e >> 4][e & 15] *= sc16; }
    __syncthreads();
#pragma unroll
    for (int j = 0; j < 4; j++) {
        int e = lane * 4 + j, r = e >> 4, c = e & 15;
        Ta[r][c] = (r == c ? 1.f : 0.f) + A16[r][c] * (1.f / 12.f);
    }
    __syncthreads();
    float (*Tc)[16] = Ta, (*Tn)[16] = Tb;
    for (int k = 11; k >= 1; k--) {
#pragma unroll
        for (int j = 0; j < 4; j++) {
            int e = lane * 4 + j, r = e >> 4, c = e & 15;
            float acc = 0.f;
#pragma unroll
            for (int q = 0; q < 16; q++) acc += A16[r][q] * Tc[q][c];
            Tn[r][c] = acc * (1.f / (float)k) + (r == c ? 1.f : 0.f);
        }
        __syncthreads();
        float (*tmp)[16] = Tc; Tc = Tn; Tn = tmp;
    }
    for (int it = 0; it < s; it++) {
#pragma unroll
        for (int j = 0; j < 4; j++) {
            int e = lane * 4 + j, r = e >> 4, c = e & 15;
            float acc = 0.f;
#pragma unroll
            for (int q = 0; q < 16; q++) acc += Tc[r][q] * Tc[q][c];
            Tn[r][c] = acc;
        }
        __syncthreads();
        float (*tmp)[16] = Tc; Tc = Tn; Tn = tmp;
    }

    float (*R2p)[8] = T8a[0];
    float (*R3p)[8] = T8a[1];
    {
        int r = lane >> 3, c = lane & 7;
        for (int m = 0; m < 2; m++) {
            float rn8 = 0.f;
            if (lane < 8) {
#pragma unroll
                for (int cc = 0; cc < 8; cc++) rn8 += fabsf(A8[m][lane][cc]);
            }
#pragma unroll
            for (int mm = 1; mm < 8; mm <<= 1) rn8 = fmaxf(rn8, __shfl_xor(rn8, mm));
            rn8 = __shfl(rn8, 0);
            int s8 = 0;
            while (rn8 > 0.5f && s8 < 60) { rn8 *= 0.5f; s8++; }
            float sc8 = exp2f((float)(-s8));
            __syncthreads();
            A8[m][r][c] *= sc8;
            __syncthreads();
            T8a[m][r][c] = (r == c ? 1.f : 0.f) + A8[m][r][c] * (1.f / 12.f);
            __syncthreads();
            float (*tc)[8] = T8a[m], (*tn)[8] = T8b[m];
            for (int k = 11; k >= 1; k--) {
                float acc = 0.f;
#pragma unroll
                for (int q = 0; q < 8; q++) acc += A8[m][r][q] * tc[q][c];
                tn[r][c] = acc * (1.f / (float)k) + (r == c ? 1.f : 0.f);
                __syncthreads();
                float (*tmp)[8] = tc; tc = tn; tn = tmp;
            }
            for (int it = 0; it < s8; it++) {
                float acc = 0.f;
#pragma unroll
                for (int q = 0; q < 8; q++) acc += tc[r][q] * tc[q][c];
                tn[r][c] = acc;
                __syncthreads();
                float (*tmp)[8] = tc; tc = tn; tn = tmp;
            }
            if (m == 0) R2p = tc; else R3p = tc;
        }
    }
    __syncthreads();

    for (int o = lane; o < 1024; o += 64) {
        int c = o & 7, base = o & ~7;
        float acc = 0.f;
#pragma unroll
        for (int j = 0; j < 8; j++) acc += R3p[c][j] * xt[base + j];
        t1[o] = acc;
    }
    __syncthreads();
    for (int o = lane; o < 1024; o += 64) {
        int c = o & 7, bb = (o >> 3) & 7, a = o >> 6;
        float acc = 0.f;
#pragma unroll
        for (int j = 0; j < 8; j++) acc += R2p[bb][j] * t1[a * 64 + j * 8 + c];
        t2[o] = acc;
    }
    __syncthreads();
    for (int o = lane; o < 1024; o += 64) {
        int rr = o & 63, a = o >> 6;
        float acc = 0.f;
#pragma unroll
        for (int j = 0; j < 16; j++) acc += Tc[a][j] * t2[j * 64 + rr];
        y[(size_t)tok * NC + o] = acc;
    }
}

// ---------------- launcher ----------------
extern "C" void kernel_launch(void* const* d_in, const int* in_sizes, int n_in,
                              void* d_out, int out_size, void* d_ws, size_t ws_size,
                              hipStream_t stream) {
    const float* x   = (const float*)d_in[0];
    const float* ck  = (const float*)d_in[1];
    const float* cv  = (const float*)d_in[2];
    const float* wqk = (const float*)d_in[3];
    const float* wv  = (const float*)d_in[4];

    float* out_y = (float*)d_out;
    float* out_k = out_y + (size_t)NB * NT * NC;
    float* out_v = out_k + (size_t)NB * NH * KV * DKK;

    char* ws = (char*)d_ws;
    _Float16* xh   = (_Float16*)ws;  ws += (size_t)NB * NT * NC * 2;
    _Float16* wqkh = (_Float16*)ws;  ws += (size_t)2 * NH * DKK * NC * 2;
    _Float16* wvh  = (_Float16*)ws;  ws += (size_t)NH * DV * NC * 2;
    _Float16* qh   = (_Float16*)ws;  ws += (size_t)NB * NH * NT * DKK * 2;
    _Float16* kh   = (_Float16*)ws;  ws += (size_t)NB * NH * KV * DKK * 2;
    _Float16* vTh  = (_Float16*)ws;  ws += (size_t)NB * NH * DV * KV * 2;
    float*    rotb = (float*)ws;     ws += (size_t)NB * NT * DV * 4;

    const int nx  = NB * NT * NC;
    const int nqk = 2 * NH * DKK * NC;
    const int nwv = NH * DV * NC;
    const int nrot = NB * NT * DV;

    k_f2h4<<<dim3((nx / 4 + 255) / 256), dim3(256), 0, stream>>>(x, xh, nx);
    k_f2h4<<<dim3((nqk / 4 + 255) / 256), dim3(256), 0, stream>>>(wqk, wqkh, nqk);
    k_f2h4<<<dim3((nwv / 4 + 255) / 256), dim3(256), 0, stream>>>(wv, wvh, nwv);
    k_zerof<<<dim3((nrot + 255) / 256), dim3(256), 0, stream>>>(rotb, nrot);

    k_copy_ck<<<dim3((NB * NH * OFF * DKK + 255) / 256), dim3(256), 0, stream>>>(ck, out_k, kh);
    k_copy_cv<<<dim3((NB * NH * OFF * DVP + 255) / 256), dim3(256), 0, stream>>>(cv, out_v, vTh);
    k_zpad_v<<<dim3((NB * NH * NT * (DVP - DV) + 255) / 256), dim3(256), 0, stream>>>(out_v);

    k_gemm_qk<<<dim3(16, 32), dim3(256), 0, stream>>>(xh, wqkh, qh, kh, out_k);
    k_gemm_v<<<dim3(22, 32), dim3(256), 0, stream>>>(xh, wvh, vTh, out_v);

    k_attn<<<dim3(1024), dim3(256), 0, stream>>>(qh, kh, vTh, rotb);

    k_rotate<<<dim3(NB * NT), dim3(64), 0, stream>>>(x, rotb, out_y);
}